// Round 13
// baseline (9959.891 us; speedup 1.0000x reference)
//
#include <hip/hip_runtime.h>

// ManyToOne GRU: N=256, L=512, I=512, H=1024.
// Round 12: round-11 kernel (6.49 ms) with the reduction restructured:
//  - R1: waves 4-7 write, waves 0-3 add (unchanged).
//  - R2: all-to-all exchange — wave w<4 writes acc for rt!=w into
//    per-(rt,src) sub-slots; after ONE barrier wave w adds the 3 foreign
//    contributions for rt==w and runs the epilogue for that rt.
//  - Barriers 6 -> 2; epilogue parallelism 1 -> 4 waves.
//  - Everything else identical: 1-limb bf16-RTN B from L2 (c-pinned XCD),
//    8-way K-split, in-place f32 h, bf16 h exchange, per-step launches.

typedef unsigned short u16;
typedef unsigned int   u32;
typedef __attribute__((ext_vector_type(4))) float f32x4;
typedef __attribute__((ext_vector_type(8))) short s16x8;

constexpr int NB   = 256;
constexpr int LSEQ = 512;
constexpr int ISZ  = 512;
constexpr int HSZ  = 1024;

constexpr int TILE_U16  = 48 * 1536;       // u16 per 16-col tile (1 plane)
constexpr int R2_OFF    = 16384;           // floats: R2 region after 4 R1 slots
constexpr int LDS_BYTES = 114688;          // 64KB R1 + 48KB R2

__device__ __forceinline__ u16 bf16_rtn(float f) {
    union { float f; u32 u; } v; v.f = f;
    u32 u = v.u; u += 0x7FFFu + ((u >> 16) & 1u);
    return (u16)(u >> 16);
}

#define MF(a, b, c) __builtin_amdgcn_mfma_f32_16x16x32_bf16(a, b, c, 0, 0, 0)

// ---------------------------------------------------------------- prep ----
// Panel layout per tile c (u16 idx): kb*1536 + p*512 + kg*128 + col*8 + e.
// kb<16: x-part (W_ih), kb>=16: h-part (W_hh). p: 0=r, 1=z, 2=n.
__global__ __launch_bounds__(256) void prep_kernel(
    const float* __restrict__ W_ih, const float* __restrict__ W_hh,
    const float* __restrict__ b_ih, const float* __restrict__ b_hh,
    const float* __restrict__ W_out,
    u16* __restrict__ Bw, float* __restrict__ Wt, float4* __restrict__ bias4)
{
    int idx = blockIdx.x * 256 + threadIdx.x;
    if (idx < 64 * TILE_U16) {
        int c   = idx / TILE_U16;
        int r1  = idx % TILE_U16;
        int kb  = r1 / 1536;
        int r2  = r1 % 1536;
        int p   = r2 / 512;
        int r3  = r2 % 512;
        int kg  = r3 >> 7;
        int col = (r3 >> 3) & 15;
        int e   = r3 & 7;
        int kloc = kg * 8 + e;
        int gcol = c * 16 + col;
        float w;
        if (kb < 16) w = W_ih[(p * HSZ + gcol) * ISZ + kb * 32 + kloc];
        else         w = W_hh[(p * HSZ + gcol) * HSZ + (kb - 16) * 32 + kloc];
        Bw[idx] = bf16_rtn(w);
    }
    if (idx < HSZ * ISZ) {           // Wt[k][i] = W_out[i][k]
        int i = idx % ISZ, k = idx / ISZ;
        Wt[idx] = W_out[i * HSZ + k];
    }
    if (idx < HSZ) {
        bias4[idx] = make_float4(b_ih[idx] + b_hh[idx],
                                 b_ih[HSZ + idx] + b_hh[HSZ + idx],
                                 b_ih[2 * HSZ + idx],
                                 b_hh[2 * HSZ + idx]);
    }
}

// ---------------------------------------------------------------- init ----
__global__ __launch_bounds__(256) void init_kernel(
    const float* __restrict__ x, const float* __restrict__ h_in,
    u16* __restrict__ xb0, float* __restrict__ hf0, u16* __restrict__ hb0)
{
    int idx = blockIdx.x * 256 + threadIdx.x;    // 131072 threads
    {
        int n = idx >> 9, k = idx & (ISZ - 1);
        xb0[idx] = bf16_rtn(x[(size_t)n * (LSEQ * ISZ) + k]);
    }
    #pragma unroll
    for (int q = 0; q < 2; ++q) {
        int e = idx * 2 + q;
        float v = h_in[e];
        hf0[e] = v;
        hb0[e] = bf16_rtn(v);
    }
}

// ---------------------------------------------------------------- step ----
__global__ __launch_bounds__(512, 1) void gru_step(
    const float* __restrict__ x, int t,
    const u16* __restrict__ Bw, const float4* __restrict__ bias4,
    const u16* __restrict__ xb, u16* __restrict__ xb_n,
    float* __restrict__ hf,
    const u16* __restrict__ hb, u16* __restrict__ hb_n)
{
    extern __shared__ float scr[];

    const int tid  = threadIdx.x;
    const int lane = tid & 63;
    const int wv   = tid >> 6;               // 0..7
    const int lr   = lane & 15;
    const int kg   = lane >> 4;
    const int raw  = blockIdx.x;             // 0..255
    const int c    = ((raw & 7) << 3) | ((raw >> 3) & 7);  // XCD raw&7: 8 tiles
    const int m    = raw >> 6;
    const int fro  = kg * 128 + lr * 8;      // u16 offset within 1KB panel

    // ---- x_{t+1} conversion: 1 elem/thread (256 WG x 512 = NB*ISZ) ----
    if (t + 1 < LSEQ) {
        int e = raw * 512 + tid;
        int n = e >> 9, k = e & (ISZ - 1);
        xb_n[e] = bf16_rtn(x[(size_t)n * (LSEQ * ISZ) + (size_t)(t + 1) * ISZ + k]);
    }

    const u16* bt = Bw + (size_t)c * TILE_U16;

    f32x4 acc[4][4];   // [rt][set]: 0=r, 1=z, 2=n_x, 3=n_h
    #pragma unroll
    for (int rt = 0; rt < 4; ++rt)
        #pragma unroll
        for (int s = 0; s < 4; ++s) acc[rt][s] = (f32x4){0.f, 0.f, 0.f, 0.f};

    // ---- main: wave wv owns kb = 6wv .. 6wv+5, straight from L2 ----
    #pragma unroll 2
    for (int j = 0; j < 6; ++j) {
        const int kb = wv * 6 + j;
        const u16* gh = bt + kb * 1536 + fro;
        s16x8 b0 = *(const s16x8*)gh;
        s16x8 b1 = *(const s16x8*)(gh + 512);
        s16x8 b2 = *(const s16x8*)(gh + 1024);
        const bool isx = (kb < 16);          // wave-uniform
        s16x8 a[4];
        if (isx) {
            #pragma unroll
            for (int rt = 0; rt < 4; ++rt) {
                const int row = m * 64 + rt * 16 + lr;
                a[rt] = *(const s16x8*)(xb + row * ISZ + kb * 32 + kg * 8);
            }
        } else {
            #pragma unroll
            for (int rt = 0; rt < 4; ++rt) {
                const int row = m * 64 + rt * 16 + lr;
                a[rt] = *(const s16x8*)(hb + row * HSZ + (kb - 16) * 32 + kg * 8);
            }
        }
        #pragma unroll
        for (int rt = 0; rt < 4; ++rt) {
            acc[rt][0] = MF(a[rt], b0, acc[rt][0]);
            acc[rt][1] = MF(a[rt], b1, acc[rt][1]);
        }
        if (isx) {
            #pragma unroll
            for (int rt = 0; rt < 4; ++rt)
                acc[rt][2] = MF(a[rt], b2, acc[rt][2]);
        } else {
            #pragma unroll
            for (int rt = 0; rt < 4; ++rt)
                acc[rt][3] = MF(a[rt], b2, acc[rt][3]);
        }
    }

    // ---- R1: waves 4-7 -> slots 0-3; waves 0-3 add (pairs (w, w+4)) ----
    if (wv >= 4) {
        float* sp = scr + (wv - 4) * 4096 + lane * 4;
        #pragma unroll
        for (int rt = 0; rt < 4; ++rt)
            #pragma unroll
            for (int s = 0; s < 4; ++s)
                *(f32x4*)(sp + (rt * 4 + s) * 256) = acc[rt][s];
    }
    __syncthreads();                                       // b1
    if (wv < 4) {
        const float* sp = scr + wv * 4096 + lane * 4;
        #pragma unroll
        for (int rt = 0; rt < 4; ++rt)
            #pragma unroll
            for (int s = 0; s < 4; ++s)
                acc[rt][s] += *(const f32x4*)(sp + (rt * 4 + s) * 256);

        // ---- R2 write: my sums for the 3 row-tiles I don't own ----
        // sub-slot (rt, src w): idx = rt*3 + (w<rt ? w : w-1), 1024 floats
        #pragma unroll
        for (int rt = 0; rt < 4; ++rt) {
            if (rt == wv) continue;
            const int sub = rt * 3 + ((wv < rt) ? wv : wv - 1);
            float* sp2 = scr + R2_OFF + sub * 1024 + lane * 4;
            #pragma unroll
            for (int s = 0; s < 4; ++s)
                *(f32x4*)(sp2 + s * 256) = acc[rt][s];
        }
    }
    __syncthreads();                                       // b2
    if (wv < 4) {
        const int rt = wv;                                 // my row-tile
        #pragma unroll
        for (int src = 0; src < 3; ++src) {
            const float* sp2 = scr + R2_OFF + (rt * 3 + src) * 1024 + lane * 4;
            #pragma unroll
            for (int s = 0; s < 4; ++s)
                acc[rt][s] += *(const f32x4*)(sp2 + s * 256);
        }
        // ---- epilogue (4 waves in parallel, one rt each) ----
        const int j = c * 16 + lr;
        const float4 b4 = bias4[j];
        #pragma unroll
        for (int i = 0; i < 4; ++i) {
            const int row = m * 64 + rt * 16 + kg * 4 + i;
            float r_ = 1.f / (1.f + __expf(-(acc[rt][0][i] + b4.x)));
            float z_ = 1.f / (1.f + __expf(-(acc[rt][1][i] + b4.y)));
            float pre = (acc[rt][2][i] + b4.z) + r_ * (acc[rt][3][i] + b4.w);
            float e2 = __expf(2.f * pre);
            float ng = 1.f - 2.f / (e2 + 1.f);
            float ho = hf[row * HSZ + j];
            float hn = (1.f - z_) * ng + z_ * ho;
            hf[row * HSZ + j] = hn;                        // in-place f32 state
            hb_n[row * HSZ + j] = bf16_rtn(hn);
        }
    }
}

// ---------------------------------------------------------------- head ----
__global__ __launch_bounds__(256) void head_kernel(
    const float* __restrict__ hfin, const float* __restrict__ Wt,
    const float* __restrict__ b_out, float* __restrict__ out)
{
    __shared__ float hrow[HSZ];
    const int n = blockIdx.x;
    const int tid = threadIdx.x;
    for (int k = tid; k < HSZ; k += 256) {
        float v = hfin[n * HSZ + k];
        hrow[k] = v;
        out[NB * ISZ + n * HSZ + k] = v;   // h_final output
    }
    __syncthreads();
    for (int j = tid; j < ISZ; j += 256) {
        float acc = b_out[j];
        #pragma unroll 8
        for (int k = 0; k < HSZ; ++k)
            acc = fmaf(hrow[k], Wt[k * ISZ + j], acc);
        out[n * ISZ + j] = acc;
    }
}

// -------------------------------------------------------------- launch ----
extern "C" void kernel_launch(void* const* d_in, const int* in_sizes, int n_in,
                              void* d_out, int out_size, void* d_ws, size_t ws_size,
                              hipStream_t stream) {
    (void)in_sizes; (void)n_in; (void)out_size; (void)ws_size;
    const float* x     = (const float*)d_in[0];
    const float* h_in  = (const float*)d_in[1];
    const float* W_ih  = (const float*)d_in[2];
    const float* b_ih  = (const float*)d_in[3];
    const float* W_hh  = (const float*)d_in[4];
    const float* b_hh  = (const float*)d_in[5];
    const float* W_out = (const float*)d_in[6];
    const float* b_out = (const float*)d_in[7];
    float* out = (float*)d_out;

    char* ws = (char*)d_ws;
    size_t o = 0;
    u16*    Bw    = (u16*)(ws + o);    o += (size_t)64 * TILE_U16 * 2; // 9,437,184
    float*  Wt    = (float*)(ws + o);  o += (size_t)HSZ * ISZ * 4;     // 2,097,152
    float4* bias4 = (float4*)(ws + o); o += (size_t)HSZ * 16;          //    16,384
    float*  hf    = (float*)(ws + o);  o += (size_t)NB * HSZ * 4;      // 1,048,576
    u16* hb[2]; u16* xb[2];
    for (int b = 0; b < 2; ++b) { hb[b] = (u16*)(ws + o); o += (size_t)NB * HSZ * 2; }
    for (int b = 0; b < 2; ++b) { xb[b] = (u16*)(ws + o); o += (size_t)NB * ISZ * 2; }
    // total ~14.2 MB

    prep_kernel<<<(64 * TILE_U16) / 256, 256, 0, stream>>>(
        W_ih, W_hh, b_ih, b_hh, W_out, Bw, Wt, bias4);
    init_kernel<<<(NB * ISZ) / 256, 256, 0, stream>>>(
        x, h_in, xb[0], hf, hb[0]);

    for (int t = 0; t < LSEQ; ++t) {
        const int cur = t & 1, nxt = cur ^ 1;
        gru_step<<<256, 512, LDS_BYTES, stream>>>(
            x, t, Bw, bias4,
            xb[cur], xb[nxt],
            hf, hb[cur], hb[nxt]);
    }
    head_kernel<<<NB, 256, 0, stream>>>(hf, Wt, b_out, out);
}

// Round 16
// 6493.423 us; speedup vs baseline: 1.5338x; 1.5338x over previous
//
#include <hip/hip_runtime.h>

// ManyToOne GRU: N=256, L=512, I=512, H=1024.
// Round 15: REVERT to round 11 exactly — the best passing configuration
// (6.49 ms, absmax 0.0039). Rounds 12-14 established that every deviation
// from this shape (funnel restructure, >64KB LDS, 512-WG/32-row occupancy
// decomposition) regresses or breaks; banking the known-good kernel.
//  - Per-step kernels, 256 WGs x 512 thr (8 waves), WG = 16 cols x 64 rows.
//  - 1-limb bf16-RTN B read straight from L2 (c-pinned XCD swizzle).
//  - 8-way K-split (6 kb/wave), 6-barrier funnel reduction (64 KB LDS),
//    single-wave epilogue, in-place f32 h blend, bf16 h exchange.

typedef unsigned short u16;
typedef unsigned int   u32;
typedef __attribute__((ext_vector_type(4))) float f32x4;
typedef __attribute__((ext_vector_type(8))) short s16x8;

constexpr int NB   = 256;
constexpr int LSEQ = 512;
constexpr int ISZ  = 512;
constexpr int HSZ  = 1024;

constexpr int TILE_U16  = 48 * 1536;       // u16 per 16-col tile (1 plane)
constexpr int LDS_BYTES = 65536;           // 4 reduction slots * 16 KB

__device__ __forceinline__ u16 bf16_rtn(float f) {
    union { float f; u32 u; } v; v.f = f;
    u32 u = v.u; u += 0x7FFFu + ((u >> 16) & 1u);
    return (u16)(u >> 16);
}

#define MF(a, b, c) __builtin_amdgcn_mfma_f32_16x16x32_bf16(a, b, c, 0, 0, 0)

// ---------------------------------------------------------------- prep ----
// Panel layout per tile c (u16 idx): kb*1536 + p*512 + kg*128 + col*8 + e.
// kb<16: x-part (W_ih), kb>=16: h-part (W_hh). p: 0=r, 1=z, 2=n.
__global__ __launch_bounds__(256) void prep_kernel(
    const float* __restrict__ W_ih, const float* __restrict__ W_hh,
    const float* __restrict__ b_ih, const float* __restrict__ b_hh,
    const float* __restrict__ W_out,
    u16* __restrict__ Bw, float* __restrict__ Wt, float4* __restrict__ bias4)
{
    int idx = blockIdx.x * 256 + threadIdx.x;
    if (idx < 64 * TILE_U16) {
        int c   = idx / TILE_U16;
        int r1  = idx % TILE_U16;
        int kb  = r1 / 1536;
        int r2  = r1 % 1536;
        int p   = r2 / 512;
        int r3  = r2 % 512;
        int kg  = r3 >> 7;
        int col = (r3 >> 3) & 15;
        int e   = r3 & 7;
        int kloc = kg * 8 + e;
        int gcol = c * 16 + col;
        float w;
        if (kb < 16) w = W_ih[(p * HSZ + gcol) * ISZ + kb * 32 + kloc];
        else         w = W_hh[(p * HSZ + gcol) * HSZ + (kb - 16) * 32 + kloc];
        Bw[idx] = bf16_rtn(w);
    }
    if (idx < HSZ * ISZ) {           // Wt[k][i] = W_out[i][k]
        int i = idx % ISZ, k = idx / ISZ;
        Wt[idx] = W_out[i * HSZ + k];
    }
    if (idx < HSZ) {
        bias4[idx] = make_float4(b_ih[idx] + b_hh[idx],
                                 b_ih[HSZ + idx] + b_hh[HSZ + idx],
                                 b_ih[2 * HSZ + idx],
                                 b_hh[2 * HSZ + idx]);
    }
}

// ---------------------------------------------------------------- init ----
__global__ __launch_bounds__(256) void init_kernel(
    const float* __restrict__ x, const float* __restrict__ h_in,
    u16* __restrict__ xb0, float* __restrict__ hf0, u16* __restrict__ hb0)
{
    int idx = blockIdx.x * 256 + threadIdx.x;    // 131072 threads
    {
        int n = idx >> 9, k = idx & (ISZ - 1);
        xb0[idx] = bf16_rtn(x[(size_t)n * (LSEQ * ISZ) + k]);
    }
    #pragma unroll
    for (int q = 0; q < 2; ++q) {
        int e = idx * 2 + q;
        float v = h_in[e];
        hf0[e] = v;
        hb0[e] = bf16_rtn(v);
    }
}

// ---------------------------------------------------------------- step ----
__global__ __launch_bounds__(512, 1) void gru_step(
    const float* __restrict__ x, int t,
    const u16* __restrict__ Bw, const float4* __restrict__ bias4,
    const u16* __restrict__ xb, u16* __restrict__ xb_n,
    float* __restrict__ hf,
    const u16* __restrict__ hb, u16* __restrict__ hb_n)
{
    extern __shared__ float scr[];           // 4 slots * 4096 floats

    const int tid  = threadIdx.x;
    const int lane = tid & 63;
    const int wv   = tid >> 6;               // 0..7
    const int lr   = lane & 15;
    const int kg   = lane >> 4;
    const int raw  = blockIdx.x;             // 0..255
    const int c    = ((raw & 7) << 3) | ((raw >> 3) & 7);  // XCD raw&7: 8 tiles
    const int m    = raw >> 6;
    const int fro  = kg * 128 + lr * 8;      // u16 offset within 1KB panel

    // ---- x_{t+1} conversion: 1 elem/thread (256 WG x 512 = NB*ISZ) ----
    if (t + 1 < LSEQ) {
        int e = raw * 512 + tid;
        int n = e >> 9, k = e & (ISZ - 1);
        xb_n[e] = bf16_rtn(x[(size_t)n * (LSEQ * ISZ) + (size_t)(t + 1) * ISZ + k]);
    }

    const u16* bt = Bw + (size_t)c * TILE_U16;

    f32x4 acc[4][4];   // [rt][set]: 0=r, 1=z, 2=n_x, 3=n_h
    #pragma unroll
    for (int rt = 0; rt < 4; ++rt)
        #pragma unroll
        for (int s = 0; s < 4; ++s) acc[rt][s] = (f32x4){0.f, 0.f, 0.f, 0.f};

    // ---- main: wave wv owns kb = 6wv .. 6wv+5, straight from L2 ----
    #pragma unroll 2
    for (int j = 0; j < 6; ++j) {
        const int kb = wv * 6 + j;
        const u16* gh = bt + kb * 1536 + fro;
        s16x8 b0 = *(const s16x8*)gh;
        s16x8 b1 = *(const s16x8*)(gh + 512);
        s16x8 b2 = *(const s16x8*)(gh + 1024);
        const bool isx = (kb < 16);          // wave-uniform
        s16x8 a[4];
        if (isx) {
            #pragma unroll
            for (int rt = 0; rt < 4; ++rt) {
                const int row = m * 64 + rt * 16 + lr;
                a[rt] = *(const s16x8*)(xb + row * ISZ + kb * 32 + kg * 8);
            }
        } else {
            #pragma unroll
            for (int rt = 0; rt < 4; ++rt) {
                const int row = m * 64 + rt * 16 + lr;
                a[rt] = *(const s16x8*)(hb + row * HSZ + (kb - 16) * 32 + kg * 8);
            }
        }
        #pragma unroll
        for (int rt = 0; rt < 4; ++rt) {
            acc[rt][0] = MF(a[rt], b0, acc[rt][0]);
            acc[rt][1] = MF(a[rt], b1, acc[rt][1]);
        }
        if (isx) {
            #pragma unroll
            for (int rt = 0; rt < 4; ++rt)
                acc[rt][2] = MF(a[rt], b2, acc[rt][2]);
        } else {
            #pragma unroll
            for (int rt = 0; rt < 4; ++rt)
                acc[rt][3] = MF(a[rt], b2, acc[rt][3]);
        }
    }

    // ---- 8-way reduction tree (round-9/11 funnel): slot sl at scr+sl*4096;
    //      entry (rt*4+set)*256 + lane*4 ----
    if (wv >= 4) {                                         // R1 write
        float* sp = scr + (wv - 4) * 4096 + lane * 4;
        #pragma unroll
        for (int rt = 0; rt < 4; ++rt)
            #pragma unroll
            for (int s = 0; s < 4; ++s)
                *(f32x4*)(sp + (rt * 4 + s) * 256) = acc[rt][s];
    }
    __syncthreads();                                       // b1
    if (wv < 4) {                                          // R1 add
        const float* sp = scr + wv * 4096 + lane * 4;
        #pragma unroll
        for (int rt = 0; rt < 4; ++rt)
            #pragma unroll
            for (int s = 0; s < 4; ++s)
                acc[rt][s] += *(const f32x4*)(sp + (rt * 4 + s) * 256);
    }
    __syncthreads();                                       // b2
    if (wv == 2 || wv == 3) {                              // R2 write
        float* sp = scr + (wv - 2) * 4096 + lane * 4;
        #pragma unroll
        for (int rt = 0; rt < 4; ++rt)
            #pragma unroll
            for (int s = 0; s < 4; ++s)
                *(f32x4*)(sp + (rt * 4 + s) * 256) = acc[rt][s];
    }
    __syncthreads();                                       // b3
    if (wv < 2) {                                          // R2 add
        const float* sp = scr + wv * 4096 + lane * 4;
        #pragma unroll
        for (int rt = 0; rt < 4; ++rt)
            #pragma unroll
            for (int s = 0; s < 4; ++s)
                acc[rt][s] += *(const f32x4*)(sp + (rt * 4 + s) * 256);
    }
    __syncthreads();                                       // b4
    if (wv == 1) {                                         // R3 write
        float* sp = scr + lane * 4;
        #pragma unroll
        for (int rt = 0; rt < 4; ++rt)
            #pragma unroll
            for (int s = 0; s < 4; ++s)
                *(f32x4*)(sp + (rt * 4 + s) * 256) = acc[rt][s];
    }
    __syncthreads();                                       // b5
    if (wv == 0) {                                         // R3 add + epilogue
        const float* sp = scr + lane * 4;
        #pragma unroll
        for (int rt = 0; rt < 4; ++rt)
            #pragma unroll
            for (int s = 0; s < 4; ++s)
                acc[rt][s] += *(const f32x4*)(sp + (rt * 4 + s) * 256);
        const int j = c * 16 + lr;
        const float4 b4 = bias4[j];
        #pragma unroll
        for (int rt = 0; rt < 4; ++rt) {
            #pragma unroll
            for (int i = 0; i < 4; ++i) {
                const int row = m * 64 + rt * 16 + kg * 4 + i;
                float r_ = 1.f / (1.f + __expf(-(acc[rt][0][i] + b4.x)));
                float z_ = 1.f / (1.f + __expf(-(acc[rt][1][i] + b4.y)));
                float pre = (acc[rt][2][i] + b4.z) + r_ * (acc[rt][3][i] + b4.w);
                float e2 = __expf(2.f * pre);
                float ng = 1.f - 2.f / (e2 + 1.f);
                float ho = hf[row * HSZ + j];
                float hn = (1.f - z_) * ng + z_ * ho;
                hf[row * HSZ + j] = hn;                    // in-place f32 state
                hb_n[row * HSZ + j] = bf16_rtn(hn);
            }
        }
    }
}

// ---------------------------------------------------------------- head ----
__global__ __launch_bounds__(256) void head_kernel(
    const float* __restrict__ hfin, const float* __restrict__ Wt,
    const float* __restrict__ b_out, float* __restrict__ out)
{
    __shared__ float hrow[HSZ];
    const int n = blockIdx.x;
    const int tid = threadIdx.x;
    for (int k = tid; k < HSZ; k += 256) {
        float v = hfin[n * HSZ + k];
        hrow[k] = v;
        out[NB * ISZ + n * HSZ + k] = v;   // h_final output
    }
    __syncthreads();
    for (int j = tid; j < ISZ; j += 256) {
        float acc = b_out[j];
        #pragma unroll 8
        for (int k = 0; k < HSZ; ++k)
            acc = fmaf(hrow[k], Wt[k * ISZ + j], acc);
        out[n * ISZ + j] = acc;
    }
}

// -------------------------------------------------------------- launch ----
extern "C" void kernel_launch(void* const* d_in, const int* in_sizes, int n_in,
                              void* d_out, int out_size, void* d_ws, size_t ws_size,
                              hipStream_t stream) {
    (void)in_sizes; (void)n_in; (void)out_size; (void)ws_size;
    const float* x     = (const float*)d_in[0];
    const float* h_in  = (const float*)d_in[1];
    const float* W_ih  = (const float*)d_in[2];
    const float* b_ih  = (const float*)d_in[3];
    const float* W_hh  = (const float*)d_in[4];
    const float* b_hh  = (const float*)d_in[5];
    const float* W_out = (const float*)d_in[6];
    const float* b_out = (const float*)d_in[7];
    float* out = (float*)d_out;

    char* ws = (char*)d_ws;
    size_t o = 0;
    u16*    Bw    = (u16*)(ws + o);    o += (size_t)64 * TILE_U16 * 2; // 9,437,184
    float*  Wt    = (float*)(ws + o);  o += (size_t)HSZ * ISZ * 4;     // 2,097,152
    float4* bias4 = (float4*)(ws + o); o += (size_t)HSZ * 16;          //    16,384
    float*  hf    = (float*)(ws + o);  o += (size_t)NB * HSZ * 4;      // 1,048,576
    u16* hb[2]; u16* xb[2];
    for (int b = 0; b < 2; ++b) { hb[b] = (u16*)(ws + o); o += (size_t)NB * HSZ * 2; }
    for (int b = 0; b < 2; ++b) { xb[b] = (u16*)(ws + o); o += (size_t)NB * ISZ * 2; }
    // total ~14.2 MB

    prep_kernel<<<(64 * TILE_U16) / 256, 256, 0, stream>>>(
        W_ih, W_hh, b_ih, b_hh, W_out, Bw, Wt, bias4);
    init_kernel<<<(NB * ISZ) / 256, 256, 0, stream>>>(
        x, h_in, xb[0], hf, hb[0]);

    for (int t = 0; t < LSEQ; ++t) {
        const int cur = t & 1, nxt = cur ^ 1;
        gru_step<<<256, 512, LDS_BYTES, stream>>>(
            x, t, Bw, bias4,
            xb[cur], xb[nxt],
            hf, hb[cur], hb[nxt]);
    }
    head_kernel<<<NB, 256, 0, stream>>>(hf, Wt, b_out, out);
}